// Round 5
// baseline (394.126 us; speedup 1.0000x reference)
//
#include <hip/hip_runtime.h>
#include <math.h>

#define BB 8
#define CIN 256
#define COUT 256
#define HH 64
#define WW 64
#define OCM 27          // 18 offset + 9 mod channels
#define KTOT 2304       // tap-major: k = tap*256 + c
#define NKT 72          // K-tiles of 32

typedef unsigned int u32;
typedef unsigned short u16;

// ---------------- ws layout (bytes) ----------------
// xbf    [8][64][64][256] bf16 NHWC   at 0           (16,777,216 B)
// w2     [72][256][32]    bf16        at 16777216    ( 1,179,648 B)
// w2om   [72][32][32]     bf16        at 17956864    (   147,456 B)
// offmod [8][27][4096]    f32         at 18104320    ( 3,538,944 B)
#define WS_XBF 0
#define WS_W2 16777216
#define WS_W2OM 17956864
#define WS_OFFMOD 18104320

__device__ __forceinline__ u16 f2bf(float f) {
    u32 u = __float_as_uint(f);
    u32 r = (u + 0x7FFFu + ((u >> 16) & 1u)) >> 16;
    return (u16)r;
}

typedef __attribute__((address_space(1))) const unsigned int* gptr_t;
typedef __attribute__((address_space(3))) unsigned int* lptr_t;
__device__ __forceinline__ void gl2lds16(const void* g, void* l) {
    __builtin_amdgcn_global_load_lds((gptr_t)g, (lptr_t)l, 16, 0, 0);
}

typedef __attribute__((ext_vector_type(8))) short frag;
typedef __attribute__((ext_vector_type(4))) float f4;

// XOR-octet swizzle: octet o (8 u16) of row r at r*32 + (o^(r&3))*8.
__device__ __forceinline__ int sw_off(int row, int oct) {
    return (row << 5) + ((oct ^ (row & 3)) << 3);
}

#define BARRIER_RAW() do { asm volatile("" ::: "memory"); \
    __builtin_amdgcn_s_barrier(); asm volatile("" ::: "memory"); } while (0)

// K0: NCHW f32 -> NHWC bf16 via LDS transpose (coalesced both sides).
__global__ __launch_bounds__(256) void k_nhwc2(const float* __restrict__ x,
                                               u16* __restrict__ xbf) {
    const int y = blockIdx.x, b = blockIdx.y;
    __shared__ float T[64][65];
    const int wl = threadIdx.x & 63, g = threadIdx.x >> 6;
    for (int c0 = 0; c0 < 256; c0 += 64) {
#pragma unroll
        for (int i = 0; i < 16; ++i) {
            int c = g + i * 4;
            T[c][wl] = x[(((size_t)(b * 256 + c0 + c)) << 12) + (y << 6) + wl];
        }
        __syncthreads();
#pragma unroll
        for (int j = 0; j < 16; ++j) {
            int w = g * 16 + j;
            xbf[((((size_t)b << 12) + (y << 6) + w) << 8) + c0 + wl] = f2bf(T[wl][w]);
        }
        __syncthreads();
    }
}

// K0b: reg_w [n][c][tap] -> w2 [kt][n][32] bf16, k = tap*256 + c
__global__ void k_pack_w2(const float* __restrict__ rw, u16* __restrict__ w2) {
    int o = blockIdx.x * blockDim.x + threadIdx.x;
    if (o >= NKT * COUT * 32) return;
    int kk = o & 31;
    int n = (o >> 5) & 255;
    int kt = o >> 13;
    int k = kt * 32 + kk;
    int tap = k >> 8;
    int c = k & 255;
    w2[o] = f2bf(rw[n * KTOT + c * 9 + tap]);
}

// K0c: offset_w/mod_w -> w2om [kt][32 oc][32 kk] bf16
__global__ void k_pack_w2om(const float* __restrict__ ow, const float* __restrict__ mw,
                            u16* __restrict__ w2om) {
    int o = blockIdx.x * blockDim.x + threadIdx.x;
    if (o >= NKT * 32 * 32) return;
    int kk = o & 31;
    int oc = (o >> 5) & 31;
    int kt = o >> 10;
    int k = kt * 32 + kk;
    int tap = k >> 8;
    int c = k & 255;
    float v = 0.f;
    if (oc < 18) v = ow[oc * KTOT + c * 9 + tap];
    else if (oc < 27) v = mw[(oc - 18) * KTOT + c * 9 + tap];
    w2om[o] = f2bf(v);
}

// K1: offset/mod conv, pipelined MFMA, K split across wave-halves.
// block=(h,b), 512 thr: waves 0-3 do kt 0..35, waves 4-7 do kt 36..71; LDS reduce.
__global__ __launch_bounds__(512, 4) void k_offmod5(
    const u16* __restrict__ xbf, const u16* __restrict__ w2om,
    const float* __restrict__ ob, const float* __restrict__ mb,
    float* __restrict__ offmod)
{
    const int h = blockIdx.x, b = blockIdx.y;
    const int t = threadIdx.x;
    const int lane = t & 63, wv = t >> 6;
    const int hf = wv >> 2;         // K-half
    const int wl4 = wv & 3;
    const int th = t & 255;
    const int fr = lane & 15, q = lane >> 4;
    const int wm = wl4 << 4;
    const int mg = th >> 2, oct = th & 3;

    __shared__ u16 AsB[2][2][64 * 32];
    __shared__ u16 BsB[2][2][32 * 32];
    __shared__ float red[64][33];

    const u16* xb = xbf + ((size_t)b << 20);
    const int kbase = hf * 36;

    auto loadA = [&](int kt, uint4* r) {
        int tap = kt >> 3;
        int yy = h + tap / 3 - 1, xx = mg + tap % 3 - 1;
        int c0 = ((kt & 7) << 5) + (oct << 3);
        uint4 v = make_uint4(0, 0, 0, 0);
        if ((unsigned)yy < HH && (unsigned)xx < WW)
            v = *(const uint4*)(xb + (((size_t)yy << 6) + xx) * 256 + c0);
        *r = v;
    };
    auto loadB = [&](int kt, uint4* r) {
        if (th < 128) *r = *(const uint4*)(w2om + (size_t)kt * 1024 + (th >> 2) * 32 + (th & 3) * 8);
    };
    auto storeAB = [&](int buf, uint4* rA, uint4* rB) {
        *(uint4*)&AsB[hf][buf][sw_off(mg, oct)] = *rA;
        if (th < 128) *(uint4*)&BsB[hf][buf][sw_off(th >> 2, th & 3)] = *rB;
    };

    f4 acc[2];
    acc[0] = (f4){0.f, 0.f, 0.f, 0.f};
    acc[1] = (f4){0.f, 0.f, 0.f, 0.f};

    uint4 rA0, rB0, rA1, rB1;
    loadA(kbase, &rA0); loadB(kbase, &rB0);
    storeAB(0, &rA0, &rB0);
    loadA(kbase + 1, &rA1); loadB(kbase + 1, &rB1);
    asm volatile("s_waitcnt lgkmcnt(0)" ::: "memory");

    auto body = [&](int i, int p, uint4* cA, uint4* cB, uint4* nA, uint4* nB) {
        BARRIER_RAW();
        frag a  = *(const frag*)&AsB[hf][p][sw_off(wm + fr, q)];
        frag b0 = *(const frag*)&BsB[hf][p][sw_off(fr, q)];
        frag b1 = *(const frag*)&BsB[hf][p][sw_off(16 + fr, q)];
        if (i + 2 < 36) { loadA(kbase + i + 2, nA); loadB(kbase + i + 2, nB); }
        if (i + 1 < 36) storeAB(1 - p, cA, cB);
        acc[0] = __builtin_amdgcn_mfma_f32_16x16x32_bf16(a, b0, acc[0], 0, 0, 0);
        acc[1] = __builtin_amdgcn_mfma_f32_16x16x32_bf16(a, b1, acc[1], 0, 0, 0);
        asm volatile("s_waitcnt lgkmcnt(0)" ::: "memory");
    };
    for (int i = 0; i < 36; i += 2) {
        body(i, 0, &rA1, &rB1, &rA0, &rB0);
        body(i + 1, 1, &rA0, &rB0, &rA1, &rB1);
    }

    // ---- K-half reduction ----
    if (hf == 1) {
#pragma unroll
        for (int ni = 0; ni < 2; ++ni)
#pragma unroll
            for (int r = 0; r < 4; ++r)
                red[wm + q * 4 + r][ni * 16 + fr] = acc[ni][r];
    }
    __syncthreads();
    if (hf == 0) {
#pragma unroll
        for (int ni = 0; ni < 2; ++ni) {
            int oc = ni * 16 + fr;
            if (oc >= OCM) continue;
            bool is_off = oc < 18;
            float bias = is_off ? ob[oc] : mb[oc - 18];
            float4 v;
            float* vp = (float*)&v;
#pragma unroll
            for (int r = 0; r < 4; ++r) {
                float s = acc[ni][r] + red[wm + q * 4 + r][oc] + bias;
                vp[r] = is_off ? fminf(fmaxf(s, -16.f), 16.f)
                               : 1.f / (1.f + __expf(-s));
            }
            *(float4*)&offmod[(((size_t)b * OCM + oc) << 12) + (h << 6) + wm + q * 4] = v;
        }
    }
}

// K2: deformable conv, producer/consumer wave specialization.
// block=(h,b), 512 thr: waves 0-3 = MFMA consumers (64m x 256n, wave 64x64),
// waves 4-7 = producers (B gl2lds staging + corner gather + interp -> LDS).
__global__ __launch_bounds__(512, 4) void k_deform5(
    const u16* __restrict__ xbf, const float* __restrict__ offmod,
    const u16* __restrict__ w2, float* __restrict__ out)
{
    const int t = threadIdx.x;
    const int h = blockIdx.x, b = blockIdx.y;
    const int lane = t & 63, wv = t >> 6;

    __shared__ int   SIDX[9][4][64];
    __shared__ float SW[9][4][64];
    __shared__ u16 AsB[2][64 * 32];
    __shared__ u16 BsB[2][256 * 32];

    // ---- sample tables: 9 taps x 64 w (all 512 threads) ----
    const float* om = offmod + (size_t)b * OCM * 4096;
    for (int e = t; e < 9 * 64; e += 512) {
        int m = e & 63, tap = e >> 6;
        float dy = om[(tap * 2) * 4096 + h * 64 + m];
        float dx = om[(tap * 2 + 1) * 4096 + h * 64 + m];
        float mv = om[(18 + tap) * 4096 + h * 64 + m];
        float py = dy + (float)(tap / 3) + (float)(h - 1);
        float px = dx + (float)(tap % 3) + (float)(m - 1);
        float y0f = floorf(py), x0f = floorf(px);
        float ly = py - y0f, lx = px - x0f;
        int y0 = (int)y0f, x0 = (int)x0f;
        int   ysr[2] = {y0, y0 + 1};
        int   xsr[2] = {x0, x0 + 1};
        float wy[2] = {1.f - ly, ly};
        float wx[2] = {1.f - lx, lx};
#pragma unroll
        for (int r = 0; r < 4; ++r) {
            int yy = ysr[r >> 1], xx = xsr[r & 1];
            bool ok = ((unsigned)yy < HH) && ((unsigned)xx < WW);
            int yc = min(max(yy, 0), HH - 1);
            int xc = min(max(xx, 0), WW - 1);
            SIDX[tap][r][m] = yc * WW + xc;
            SW[tap][r][m] = ok ? (wy[r >> 1] * wx[r & 1] * mv) : 0.f;
        }
    }
    __syncthreads();

    if (wv < 4) {
        // ================= consumers: pure MFMA =================
        const int fr = lane & 15, q = lane >> 4;
        const int wn = wv << 6;

        f4 acc[4][4];
#pragma unroll
        for (int mi = 0; mi < 4; ++mi)
#pragma unroll
            for (int ni = 0; ni < 4; ++ni) acc[mi][ni] = (f4){0.f, 0.f, 0.f, 0.f};

        for (int kt = 0; kt < NKT; ++kt) {
            const int p = kt & 1;
            BARRIER_RAW();
            frag a[4], bq[4];
#pragma unroll
            for (int mi = 0; mi < 4; ++mi)
                a[mi] = *(const frag*)&AsB[p][sw_off(mi * 16 + fr, q)];
#pragma unroll
            for (int ni = 0; ni < 4; ++ni)
                bq[ni] = *(const frag*)&BsB[p][sw_off(wn + ni * 16 + fr, q)];
#pragma unroll
            for (int mi = 0; mi < 4; ++mi)
#pragma unroll
                for (int ni = 0; ni < 4; ++ni)
                    acc[mi][ni] = __builtin_amdgcn_mfma_f32_16x16x32_bf16(
                        a[mi], bq[ni], acc[mi][ni], 0, 0, 0);
        }

        // epilogue: out[b][n][h*64+w]; C/D col=fr(n), row=q*4+r(m)
#pragma unroll
        for (int ni = 0; ni < 4; ++ni) {
            int n_g = wn + ni * 16 + fr;
            float* outn = out + (((size_t)b * COUT + n_g) << 12) + (h << 6);
#pragma unroll
            for (int mi = 0; mi < 4; ++mi) {
                int wl = mi * 16 + q * 4;
                *(float4*)&outn[wl] = make_float4(acc[mi][ni][0], acc[mi][ni][1],
                                                  acc[mi][ni][2], acc[mi][ni][3]);
            }
        }
    } else {
        // ================= producers: gather + interp + staging =================
        const int pt = t - 256;            // 0..255
        const int mg = pt >> 2, oct = pt & 3;
        const int pwv = wv - 4;            // 0..3
        const int ko_sw = (lane & 3) ^ ((lane >> 2) & 3);
        const u16* xpl = xbf + ((size_t)b << 20);

        auto stageB = [&](int kt, int buf) {
            const u16* src = w2 + ((size_t)kt << 13);
#pragma unroll
            for (int j = 0; j < 4; ++j) {
                int n = (pwv << 6) + (j << 4) + (lane >> 2);
                u16* dst = &BsB[buf][((pwv << 6) + (j << 4)) << 5];  // wave-uniform base
                gl2lds16(src + n * 32 + ko_sw * 8, dst);
            }
        };
        auto loadCorners = [&](int kt, uint4* cr) {
            int tap = kt >> 3;
            int c0 = ((kt & 7) << 5) + (oct << 3);
            const u16* base = xpl + c0;
#pragma unroll
            for (int r = 0; r < 4; ++r)
                cr[r] = *(const uint4*)(base + ((size_t)SIDX[tap][r][mg] << 8));
        };
        auto interpStore = [&](int kt, int buf, uint4* cr) {
            int tap = kt >> 3;
            float va[8];
#pragma unroll
            for (int j = 0; j < 8; ++j) va[j] = 0.f;
#pragma unroll
            for (int r = 0; r < 4; ++r) {
                float s = SW[tap][r][mg];
                u32 uu[4] = {cr[r].x, cr[r].y, cr[r].z, cr[r].w};
#pragma unroll
                for (int jj = 0; jj < 4; ++jj) {
                    va[2 * jj]     += s * __uint_as_float(uu[jj] << 16);
                    va[2 * jj + 1] += s * __uint_as_float(uu[jj] & 0xFFFF0000u);
                }
            }
            u32 pk[4];
#pragma unroll
            for (int jp = 0; jp < 4; ++jp)
                pk[jp] = (u32)f2bf(va[2 * jp]) | ((u32)f2bf(va[2 * jp + 1]) << 16);
            *(uint4*)&AsB[buf][sw_off(mg, oct)] = make_uint4(pk[0], pk[1], pk[2], pk[3]);
        };

        uint4 crA[4], crB[4];
        // prologue: B(0)->buf0, corners(0)->crA, corners(1)->crB, interp(0)->As0
        stageB(0, 0);
        loadCorners(0, crA);
        loadCorners(1, crB);
        interpStore(0, 0, crA);
        asm volatile("s_waitcnt lgkmcnt(0)" ::: "memory");

        for (int kt = 0; kt < NKT; ++kt) {
            const int p = kt & 1;
            uint4* cur = (kt & 1) ? crA : crB;   // corners(kt+1)
            uint4* nxt = (kt & 1) ? crB : crA;   // dest for corners(kt+2)
            // B(kt) must be landed before the barrier; corners(kt+1) may fly.
            if (kt == NKT - 1) asm volatile("s_waitcnt vmcnt(0)" ::: "memory");
            else               asm volatile("s_waitcnt vmcnt(4)" ::: "memory");
            BARRIER_RAW();
            if (kt + 1 < NKT) stageB(kt + 1, 1 - p);
            if (kt + 2 < NKT) loadCorners(kt + 2, nxt);
            if (kt + 1 < NKT) interpStore(kt + 1, 1 - p, cur);
            asm volatile("s_waitcnt lgkmcnt(0)" ::: "memory");
        }
    }
}

extern "C" void kernel_launch(void* const* d_in, const int* in_sizes, int n_in,
                              void* d_out, int out_size, void* d_ws, size_t ws_size,
                              hipStream_t stream) {
    const float* x  = (const float*)d_in[0];
    const float* ow = (const float*)d_in[1];
    const float* ob = (const float*)d_in[2];
    const float* mw = (const float*)d_in[3];
    const float* mb = (const float*)d_in[4];
    const float* rw = (const float*)d_in[5];
    float* out = (float*)d_out;
    char* ws = (char*)d_ws;

    u16*   xbf    = (u16*)(ws + WS_XBF);
    u16*   w2     = (u16*)(ws + WS_W2);
    u16*   w2om   = (u16*)(ws + WS_W2OM);
    float* offmod = (float*)(ws + WS_OFFMOD);

    k_nhwc2<<<dim3(HH, BB), 256, 0, stream>>>(x, xbf);
    k_pack_w2<<<(NKT * COUT * 32 + 255) / 256, 256, 0, stream>>>(rw, w2);
    k_pack_w2om<<<(NKT * 32 * 32 + 255) / 256, 256, 0, stream>>>(ow, mw, w2om);
    k_offmod5<<<dim3(HH, BB), 512, 0, stream>>>(xbf, w2om, ob, mb, offmod);
    k_deform5<<<dim3(HH, BB), 512, 0, stream>>>(xbf, offmod, w2, out);
}

// Round 6
// 204.665 us; speedup vs baseline: 1.9257x; 1.9257x over previous
//
#include <hip/hip_runtime.h>
#include <math.h>

#define BB 8
#define CIN 256
#define COUT 256
#define HH 64
#define WW 64
#define OCM 27          // 18 offset + 9 mod channels
#define KTOT 2304       // tap-major: k = tap*256 + c
#define NKT 72          // K-tiles of 32

typedef unsigned int u32;
typedef unsigned short u16;

// ---------------- ws layout (bytes) ----------------
#define WS_XBF 0
#define WS_W2 16777216
#define WS_W2OM 17956864
#define WS_OFFMOD 18104320

__device__ __forceinline__ u16 f2bf(float f) {
    u32 u = __float_as_uint(f);
    u32 r = (u + 0x7FFFu + ((u >> 16) & 1u)) >> 16;
    return (u16)r;
}

typedef __attribute__((address_space(1))) const unsigned int* gptr_t;
typedef __attribute__((address_space(3))) unsigned int* lptr_t;
__device__ __forceinline__ void gl2lds16(const void* g, void* l) {
    __builtin_amdgcn_global_load_lds((gptr_t)g, (lptr_t)l, 16, 0, 0);
}

typedef __attribute__((ext_vector_type(8))) short frag;
typedef __attribute__((ext_vector_type(4))) float f4;

// XOR-octet swizzle: octet o (8 u16) of row r at r*32 + (o^(r&3))*8.
__device__ __forceinline__ int sw_off(int row, int oct) {
    return (row << 5) + ((oct ^ (row & 3)) << 3);
}

#define BARRIER_RAW() do { asm volatile("" ::: "memory"); \
    __builtin_amdgcn_s_barrier(); asm volatile("" ::: "memory"); } while (0)

// K0: NCHW f32 -> NHWC bf16 via LDS transpose (coalesced both sides).
__global__ __launch_bounds__(256) void k_nhwc2(const float* __restrict__ x,
                                               u16* __restrict__ xbf) {
    const int y = blockIdx.x, b = blockIdx.y;
    __shared__ float T[64][65];
    const int wl = threadIdx.x & 63, g = threadIdx.x >> 6;
    for (int c0 = 0; c0 < 256; c0 += 64) {
#pragma unroll
        for (int i = 0; i < 16; ++i) {
            int c = g + i * 4;
            T[c][wl] = x[(((size_t)(b * 256 + c0 + c)) << 12) + (y << 6) + wl];
        }
        __syncthreads();
#pragma unroll
        for (int j = 0; j < 16; ++j) {
            int w = g * 16 + j;
            xbf[((((size_t)b << 12) + (y << 6) + w) << 8) + c0 + wl] = f2bf(T[wl][w]);
        }
        __syncthreads();
    }
}

// K0b: reg_w [n][c][tap] -> w2 [kt][n][32] bf16, k = tap*256 + c
__global__ void k_pack_w2(const float* __restrict__ rw, u16* __restrict__ w2) {
    int o = blockIdx.x * blockDim.x + threadIdx.x;
    if (o >= NKT * COUT * 32) return;
    int kk = o & 31;
    int n = (o >> 5) & 255;
    int kt = o >> 13;
    int k = kt * 32 + kk;
    int tap = k >> 8;
    int c = k & 255;
    w2[o] = f2bf(rw[n * KTOT + c * 9 + tap]);
}

// K0c: offset_w/mod_w -> w2om [kt][32 oc][32 kk] bf16
__global__ void k_pack_w2om(const float* __restrict__ ow, const float* __restrict__ mw,
                            u16* __restrict__ w2om) {
    int o = blockIdx.x * blockDim.x + threadIdx.x;
    if (o >= NKT * 32 * 32) return;
    int kk = o & 31;
    int oc = (o >> 5) & 31;
    int kt = o >> 10;
    int k = kt * 32 + kk;
    int tap = k >> 8;
    int c = k & 255;
    float v = 0.f;
    if (oc < 18) v = ow[oc * KTOT + c * 9 + tap];
    else if (oc < 27) v = mw[(oc - 18) * KTOT + c * 9 + tap];
    w2om[o] = f2bf(v);
}

// K1: offset/mod conv, pipelined MFMA, K split across wave-halves.
__global__ __launch_bounds__(512, 4) void k_offmod5(
    const u16* __restrict__ xbf, const u16* __restrict__ w2om,
    const float* __restrict__ ob, const float* __restrict__ mb,
    float* __restrict__ offmod)
{
    const int h = blockIdx.x, b = blockIdx.y;
    const int t = threadIdx.x;
    const int lane = t & 63, wv = t >> 6;
    const int hf = wv >> 2;         // K-half
    const int wl4 = wv & 3;
    const int th = t & 255;
    const int fr = lane & 15, q = lane >> 4;
    const int wm = wl4 << 4;
    const int mg = th >> 2, oct = th & 3;

    __shared__ u16 AsB[2][2][64 * 32];
    __shared__ u16 BsB[2][2][32 * 32];
    __shared__ float red[64][33];

    const u16* xb = xbf + ((size_t)b << 20);
    const int kbase = hf * 36;

    auto loadA = [&](int kt, uint4* r) {
        int tap = kt >> 3;
        int yy = h + tap / 3 - 1, xx = mg + tap % 3 - 1;
        int c0 = ((kt & 7) << 5) + (oct << 3);
        uint4 v = make_uint4(0, 0, 0, 0);
        if ((unsigned)yy < HH && (unsigned)xx < WW)
            v = *(const uint4*)(xb + (((size_t)yy << 6) + xx) * 256 + c0);
        *r = v;
    };
    auto loadB = [&](int kt, uint4* r) {
        if (th < 128) *r = *(const uint4*)(w2om + (size_t)kt * 1024 + (th >> 2) * 32 + (th & 3) * 8);
    };
    auto storeAB = [&](int buf, uint4* rA, uint4* rB) {
        *(uint4*)&AsB[hf][buf][sw_off(mg, oct)] = *rA;
        if (th < 128) *(uint4*)&BsB[hf][buf][sw_off(th >> 2, th & 3)] = *rB;
    };

    f4 acc[2];
    acc[0] = (f4){0.f, 0.f, 0.f, 0.f};
    acc[1] = (f4){0.f, 0.f, 0.f, 0.f};

    uint4 rA0, rB0, rA1, rB1;
    loadA(kbase, &rA0); loadB(kbase, &rB0);
    storeAB(0, &rA0, &rB0);
    loadA(kbase + 1, &rA1); loadB(kbase + 1, &rB1);
    asm volatile("s_waitcnt lgkmcnt(0)" ::: "memory");

    auto body = [&](int i, int p, uint4* cA, uint4* cB, uint4* nA, uint4* nB) {
        BARRIER_RAW();
        frag a  = *(const frag*)&AsB[hf][p][sw_off(wm + fr, q)];
        frag b0 = *(const frag*)&BsB[hf][p][sw_off(fr, q)];
        frag b1 = *(const frag*)&BsB[hf][p][sw_off(16 + fr, q)];
        if (i + 2 < 36) { loadA(kbase + i + 2, nA); loadB(kbase + i + 2, nB); }
        if (i + 1 < 36) storeAB(1 - p, cA, cB);
        acc[0] = __builtin_amdgcn_mfma_f32_16x16x32_bf16(a, b0, acc[0], 0, 0, 0);
        acc[1] = __builtin_amdgcn_mfma_f32_16x16x32_bf16(a, b1, acc[1], 0, 0, 0);
        asm volatile("s_waitcnt lgkmcnt(0)" ::: "memory");
    };
    for (int i = 0; i < 36; i += 2) {
        body(i, 0, &rA1, &rB1, &rA0, &rB0);
        body(i + 1, 1, &rA0, &rB0, &rA1, &rB1);
    }

    // ---- K-half reduction ----
    if (hf == 1) {
#pragma unroll
        for (int ni = 0; ni < 2; ++ni)
#pragma unroll
            for (int r = 0; r < 4; ++r)
                red[wm + q * 4 + r][ni * 16 + fr] = acc[ni][r];
    }
    __syncthreads();
    if (hf == 0) {
#pragma unroll
        for (int ni = 0; ni < 2; ++ni) {
            int oc = ni * 16 + fr;
            if (oc >= OCM) continue;
            bool is_off = oc < 18;
            float bias = is_off ? ob[oc] : mb[oc - 18];
            float4 v;
            float* vp = (float*)&v;
#pragma unroll
            for (int r = 0; r < 4; ++r) {
                float s = acc[ni][r] + red[wm + q * 4 + r][oc] + bias;
                vp[r] = is_off ? fminf(fmaxf(s, -16.f), 16.f)
                               : 1.f / (1.f + __expf(-s));
            }
            *(float4*)&offmod[(((size_t)b * OCM + oc) << 12) + (h << 6) + wm + q * 4] = v;
        }
    }
}

// K2: deformable conv, producer/consumer wave specialization, NO dynamic
// private-array pointers (round-5 spill fix: corner buffers passed as
// compile-time array refs in a 2x-unrolled loop).
__global__ __launch_bounds__(512, 4) void k_deform6(
    const u16* __restrict__ xbf, const float* __restrict__ offmod,
    const u16* __restrict__ w2, float* __restrict__ out)
{
    const int t = threadIdx.x;
    const int h = blockIdx.x, b = blockIdx.y;
    const int lane = t & 63, wv = t >> 6;

    __shared__ int   SIDX[9][4][64];
    __shared__ float SW[9][4][64];
    __shared__ u16 AsB[2][64 * 32];
    __shared__ u16 BsB[2][256 * 32];

    // ---- sample tables: 9 taps x 64 w (all 512 threads) ----
    const float* om = offmod + (size_t)b * OCM * 4096;
    for (int e = t; e < 9 * 64; e += 512) {
        int m = e & 63, tap = e >> 6;
        float dy = om[(tap * 2) * 4096 + h * 64 + m];
        float dx = om[(tap * 2 + 1) * 4096 + h * 64 + m];
        float mv = om[(18 + tap) * 4096 + h * 64 + m];
        float py = dy + (float)(tap / 3) + (float)(h - 1);
        float px = dx + (float)(tap % 3) + (float)(m - 1);
        float y0f = floorf(py), x0f = floorf(px);
        float ly = py - y0f, lx = px - x0f;
        int y0 = (int)y0f, x0 = (int)x0f;
        int   ysr[2] = {y0, y0 + 1};
        int   xsr[2] = {x0, x0 + 1};
        float wy[2] = {1.f - ly, ly};
        float wx[2] = {1.f - lx, lx};
#pragma unroll
        for (int r = 0; r < 4; ++r) {
            int yy = ysr[r >> 1], xx = xsr[r & 1];
            bool ok = ((unsigned)yy < HH) && ((unsigned)xx < WW);
            int yc = min(max(yy, 0), HH - 1);
            int xc = min(max(xx, 0), WW - 1);
            SIDX[tap][r][m] = yc * WW + xc;
            SW[tap][r][m] = ok ? (wy[r >> 1] * wx[r & 1] * mv) : 0.f;
        }
    }
    __syncthreads();

    if (wv < 4) {
        // ================= consumers: pure MFMA =================
        const int fr = lane & 15, q = lane >> 4;
        const int wn = wv << 6;

        f4 acc[4][4];
#pragma unroll
        for (int mi = 0; mi < 4; ++mi)
#pragma unroll
            for (int ni = 0; ni < 4; ++ni) acc[mi][ni] = (f4){0.f, 0.f, 0.f, 0.f};

        for (int kt = 0; kt < NKT; ++kt) {
            const int p = kt & 1;
            BARRIER_RAW();
            frag a[4];
#pragma unroll
            for (int mi = 0; mi < 4; ++mi)
                a[mi] = *(const frag*)&AsB[p][sw_off(mi * 16 + fr, q)];
            // n-halves to bound live registers (acc64 + a16 + bq8 < 128 cap)
#pragma unroll
            for (int nh = 0; nh < 2; ++nh) {
                frag b0 = *(const frag*)&BsB[p][sw_off(wn + nh * 32 + fr, q)];
                frag b1 = *(const frag*)&BsB[p][sw_off(wn + nh * 32 + 16 + fr, q)];
#pragma unroll
                for (int mi = 0; mi < 4; ++mi) {
                    acc[mi][nh * 2]     = __builtin_amdgcn_mfma_f32_16x16x32_bf16(
                        a[mi], b0, acc[mi][nh * 2], 0, 0, 0);
                    acc[mi][nh * 2 + 1] = __builtin_amdgcn_mfma_f32_16x16x32_bf16(
                        a[mi], b1, acc[mi][nh * 2 + 1], 0, 0, 0);
                }
            }
        }

        // epilogue: out[b][n][h*64+w]; C/D col=fr(n), row=q*4+r(m)
#pragma unroll
        for (int ni = 0; ni < 4; ++ni) {
            int n_g = wn + ni * 16 + fr;
            float* outn = out + (((size_t)b * COUT + n_g) << 12) + (h << 6);
#pragma unroll
            for (int mi = 0; mi < 4; ++mi) {
                int wl = mi * 16 + q * 4;
                *(float4*)&outn[wl] = make_float4(acc[mi][ni][0], acc[mi][ni][1],
                                                  acc[mi][ni][2], acc[mi][ni][3]);
            }
        }
    } else {
        // ================= producers: gather + interp + staging =================
        const int pt = t - 256;            // 0..255
        const int mg = pt >> 2, oct = pt & 3;
        const int pwv = wv - 4;            // 0..3
        const int ko_sw = (lane & 3) ^ ((lane >> 2) & 3);
        const u16* xpl = xbf + ((size_t)b << 20);

        auto stageB = [&](int kt, int buf) {
            const u16* src = w2 + ((size_t)kt << 13);
#pragma unroll
            for (int j = 0; j < 4; ++j) {
                int n = (pwv << 6) + (j << 4) + (lane >> 2);
                u16* dst = &BsB[buf][((pwv << 6) + (j << 4)) << 5];  // wave-uniform base
                gl2lds16(src + n * 32 + ko_sw * 8, dst);
            }
        };
        auto loadCorners = [&](int kt, uint4 (&cr)[4]) {
            int tap = kt >> 3;
            int c0 = ((kt & 7) << 5) + (oct << 3);
            const u16* base = xpl + c0;
#pragma unroll
            for (int r = 0; r < 4; ++r)
                cr[r] = *(const uint4*)(base + ((size_t)SIDX[tap][r][mg] << 8));
        };
        auto interpStore = [&](int kt, int buf, uint4 (&cr)[4]) {
            int tap = kt >> 3;
            float va[8];
#pragma unroll
            for (int j = 0; j < 8; ++j) va[j] = 0.f;
#pragma unroll
            for (int r = 0; r < 4; ++r) {
                float s = SW[tap][r][mg];
                u32 uu[4] = {cr[r].x, cr[r].y, cr[r].z, cr[r].w};
#pragma unroll
                for (int jj = 0; jj < 4; ++jj) {
                    va[2 * jj]     += s * __uint_as_float(uu[jj] << 16);
                    va[2 * jj + 1] += s * __uint_as_float(uu[jj] & 0xFFFF0000u);
                }
            }
            u32 pk[4];
#pragma unroll
            for (int jp = 0; jp < 4; ++jp)
                pk[jp] = (u32)f2bf(va[2 * jp]) | ((u32)f2bf(va[2 * jp + 1]) << 16);
            *(uint4*)&AsB[buf][sw_off(mg, oct)] = make_uint4(pk[0], pk[1], pk[2], pk[3]);
        };

        uint4 crA[4], crB[4];
        // prologue: B(0)->buf0 async; corners(0)->crB; corners(1)->crA;
        // interp(0)->As0 (waits crB only).
        stageB(0, 0);
        loadCorners(0, crB);
        loadCorners(1, crA);
        interpStore(0, 0, crB);
        asm volatile("s_waitcnt lgkmcnt(0)" ::: "memory");

        // pstep(kt, p): cur holds corners(kt+1); nxt receives corners(kt+2).
        auto pstep = [&](int kt, int p, uint4 (&cur)[4], uint4 (&nxt)[4]) {
            if (kt == NKT - 1) asm volatile("s_waitcnt vmcnt(0)" ::: "memory");
            else               asm volatile("s_waitcnt vmcnt(4)" ::: "memory");
            BARRIER_RAW();
            if (kt + 1 < NKT) stageB(kt + 1, 1 - p);
            if (kt + 2 < NKT) loadCorners(kt + 2, nxt);
            if (kt + 1 < NKT) interpStore(kt + 1, 1 - p, cur);
            asm volatile("s_waitcnt lgkmcnt(0)" ::: "memory");
        };
        for (int kt = 0; kt < NKT; kt += 2) {
            pstep(kt, 0, crA, crB);
            pstep(kt + 1, 1, crB, crA);
        }
    }
}

extern "C" void kernel_launch(void* const* d_in, const int* in_sizes, int n_in,
                              void* d_out, int out_size, void* d_ws, size_t ws_size,
                              hipStream_t stream) {
    const float* x  = (const float*)d_in[0];
    const float* ow = (const float*)d_in[1];
    const float* ob = (const float*)d_in[2];
    const float* mw = (const float*)d_in[3];
    const float* mb = (const float*)d_in[4];
    const float* rw = (const float*)d_in[5];
    float* out = (float*)d_out;
    char* ws = (char*)d_ws;

    u16*   xbf    = (u16*)(ws + WS_XBF);
    u16*   w2     = (u16*)(ws + WS_W2);
    u16*   w2om   = (u16*)(ws + WS_W2OM);
    float* offmod = (float*)(ws + WS_OFFMOD);

    k_nhwc2<<<dim3(HH, BB), 256, 0, stream>>>(x, xbf);
    k_pack_w2<<<(NKT * COUT * 32 + 255) / 256, 256, 0, stream>>>(rw, w2);
    k_pack_w2om<<<(NKT * 32 * 32 + 255) / 256, 256, 0, stream>>>(ow, mw, w2om);
    k_offmod5<<<dim3(HH, BB), 512, 0, stream>>>(xbf, w2om, ob, mb, offmod);
    k_deform6<<<dim3(HH, BB), 512, 0, stream>>>(xbf, offmod, w2, out);
}

// Round 7
// 182.848 us; speedup vs baseline: 2.1555x; 1.1193x over previous
//
#include <hip/hip_runtime.h>
#include <math.h>

#define BB 8
#define CIN 256
#define COUT 256
#define HH 64
#define WW 64
#define OCM 27          // 18 offset + 9 mod channels
#define KTOT 2304       // tap-major: k = tap*256 + c
#define NKT 72          // K-tiles of 32

typedef unsigned int u32;
typedef unsigned short u16;

// ---------------- ws layout (bytes) ----------------
#define WS_XBF 0
#define WS_W2 16777216
#define WS_W2OM 17956864
#define WS_OFFMOD 18104320

__device__ __forceinline__ u16 f2bf(float f) {
    u32 u = __float_as_uint(f);
    u32 r = (u + 0x7FFFu + ((u >> 16) & 1u)) >> 16;
    return (u16)r;
}

typedef __attribute__((address_space(1))) const unsigned int* gptr_t;
typedef __attribute__((address_space(3))) unsigned int* lptr_t;
__device__ __forceinline__ void gl2lds16(const void* g, void* l) {
    __builtin_amdgcn_global_load_lds((gptr_t)g, (lptr_t)l, 16, 0, 0);
}

typedef __attribute__((ext_vector_type(8))) short frag;
typedef __attribute__((ext_vector_type(4))) float f4;

// Swizzle g(row) = (row>>1)&3: conflict-free (2-way max) for BOTH the
// staging-write phase (4 rows x 4 octs) and the frag-read phase
// (16 consecutive rows, fixed oct). R6's g=row&3 was 4-way on reads.
__device__ __forceinline__ int sw_off(int row, int oct) {
    return (row << 5) + ((oct ^ ((row >> 1) & 3)) << 3);
}

#define BARRIER_RAW() do { asm volatile("" ::: "memory"); \
    __builtin_amdgcn_s_barrier(); asm volatile("" ::: "memory"); } while (0)

// K0: NCHW f32 -> NHWC bf16 via LDS transpose; packed u32 writes.
__global__ __launch_bounds__(256) void k_nhwc3(const float* __restrict__ x,
                                               u16* __restrict__ xbf) {
    const int y = blockIdx.x, b = blockIdx.y;
    __shared__ float T[64][65];
    const int t = threadIdx.x;
    const int wl = t & 63, g = t >> 6;
    const int pr = wl & 31, wsub = wl >> 5;   // c-pair, w-subrow for write phase
    u32* xo = (u32*)xbf;
    for (int c0 = 0; c0 < 256; c0 += 64) {
#pragma unroll
        for (int i = 0; i < 16; ++i) {
            int c = g + i * 4;
            T[c][wl] = x[(((size_t)(b * 256 + c0 + c)) << 12) + (y << 6) + wl];
        }
        __syncthreads();
#pragma unroll
        for (int j = 0; j < 8; ++j) {
            int w = j * 8 + g * 2 + wsub;
            u32 v = (u32)f2bf(T[2 * pr][w]) | ((u32)f2bf(T[2 * pr + 1][w]) << 16);
            xo[((((size_t)b << 12) + (y << 6) + w) << 7) + (c0 >> 1) + pr] = v;
        }
        __syncthreads();
    }
}

// K0b: reg_w [n][c][tap] -> w2 [kt][n][32] bf16, k = tap*256 + c
__global__ void k_pack_w2(const float* __restrict__ rw, u16* __restrict__ w2) {
    int o = blockIdx.x * blockDim.x + threadIdx.x;
    if (o >= NKT * COUT * 32) return;
    int kk = o & 31;
    int n = (o >> 5) & 255;
    int kt = o >> 13;
    int k = kt * 32 + kk;
    int tap = k >> 8;
    int c = k & 255;
    w2[o] = f2bf(rw[n * KTOT + c * 9 + tap]);
}

// K0c: offset_w/mod_w -> w2om [kt][32 oc][32 kk] bf16
__global__ void k_pack_w2om(const float* __restrict__ ow, const float* __restrict__ mw,
                            u16* __restrict__ w2om) {
    int o = blockIdx.x * blockDim.x + threadIdx.x;
    if (o >= NKT * 32 * 32) return;
    int kk = o & 31;
    int oc = (o >> 5) & 31;
    int kt = o >> 10;
    int k = kt * 32 + kk;
    int tap = k >> 8;
    int c = k & 255;
    float v = 0.f;
    if (oc < 18) v = ow[oc * KTOT + c * 9 + tap];
    else if (oc < 27) v = mw[(oc - 18) * KTOT + c * 9 + tap];
    w2om[o] = f2bf(v);
}

// K1: offset/mod conv, pipelined MFMA, K split across wave-halves.
// grid: 512 linear, b = idx&7 (XCD-local batch), h = idx>>3.
__global__ __launch_bounds__(512, 4) void k_offmod6(
    const u16* __restrict__ xbf, const u16* __restrict__ w2om,
    const float* __restrict__ ob, const float* __restrict__ mb,
    float* __restrict__ offmod)
{
    const int b = blockIdx.x & 7, h = blockIdx.x >> 3;
    const int t = threadIdx.x;
    const int lane = t & 63, wv = t >> 6;
    const int hf = wv >> 2;         // K-half
    const int wl4 = wv & 3;
    const int th = t & 255;
    const int fr = lane & 15, q = lane >> 4;
    const int wm = wl4 << 4;
    const int mg = th >> 2, oct = th & 3;

    __shared__ u16 AsB[2][2][64 * 32];
    __shared__ u16 BsB[2][2][32 * 32];
    __shared__ float red[64][33];

    const u16* xb = xbf + ((size_t)b << 20);
    const int kbase = hf * 36;

    auto loadA = [&](int kt, uint4* r) {
        int tap = kt >> 3;
        int yy = h + tap / 3 - 1, xx = mg + tap % 3 - 1;
        int c0 = ((kt & 7) << 5) + (oct << 3);
        uint4 v = make_uint4(0, 0, 0, 0);
        if ((unsigned)yy < HH && (unsigned)xx < WW)
            v = *(const uint4*)(xb + (((size_t)yy << 6) + xx) * 256 + c0);
        *r = v;
    };
    auto loadB = [&](int kt, uint4* r) {
        if (th < 128) *r = *(const uint4*)(w2om + (size_t)kt * 1024 + (th >> 2) * 32 + (th & 3) * 8);
    };
    auto storeAB = [&](int buf, uint4* rA, uint4* rB) {
        *(uint4*)&AsB[hf][buf][sw_off(mg, oct)] = *rA;
        if (th < 128) *(uint4*)&BsB[hf][buf][sw_off(th >> 2, th & 3)] = *rB;
    };

    f4 acc[2];
    acc[0] = (f4){0.f, 0.f, 0.f, 0.f};
    acc[1] = (f4){0.f, 0.f, 0.f, 0.f};

    uint4 rA0, rB0, rA1, rB1;
    loadA(kbase, &rA0); loadB(kbase, &rB0);
    storeAB(0, &rA0, &rB0);
    loadA(kbase + 1, &rA1); loadB(kbase + 1, &rB1);
    asm volatile("s_waitcnt lgkmcnt(0)" ::: "memory");

    auto body = [&](int i, int p, uint4* cA, uint4* cB, uint4* nA, uint4* nB) {
        BARRIER_RAW();
        frag a  = *(const frag*)&AsB[hf][p][sw_off(wm + fr, q)];
        frag b0 = *(const frag*)&BsB[hf][p][sw_off(fr, q)];
        frag b1 = *(const frag*)&BsB[hf][p][sw_off(16 + fr, q)];
        if (i + 2 < 36) { loadA(kbase + i + 2, nA); loadB(kbase + i + 2, nB); }
        if (i + 1 < 36) storeAB(1 - p, cA, cB);
        acc[0] = __builtin_amdgcn_mfma_f32_16x16x32_bf16(a, b0, acc[0], 0, 0, 0);
        acc[1] = __builtin_amdgcn_mfma_f32_16x16x32_bf16(a, b1, acc[1], 0, 0, 0);
        asm volatile("s_waitcnt lgkmcnt(0)" ::: "memory");
    };
    for (int i = 0; i < 36; i += 2) {
        body(i, 0, &rA1, &rB1, &rA0, &rB0);
        body(i + 1, 1, &rA0, &rB0, &rA1, &rB1);
    }

    // ---- K-half reduction ----
    if (hf == 1) {
#pragma unroll
        for (int ni = 0; ni < 2; ++ni)
#pragma unroll
            for (int r = 0; r < 4; ++r)
                red[wm + q * 4 + r][ni * 16 + fr] = acc[ni][r];
    }
    __syncthreads();
    if (hf == 0) {
#pragma unroll
        for (int ni = 0; ni < 2; ++ni) {
            int oc = ni * 16 + fr;
            if (oc >= OCM) continue;
            bool is_off = oc < 18;
            float bias = is_off ? ob[oc] : mb[oc - 18];
            float4 v;
            float* vp = (float*)&v;
#pragma unroll
            for (int r = 0; r < 4; ++r) {
                float s = acc[ni][r] + red[wm + q * 4 + r][oc] + bias;
                vp[r] = is_off ? fminf(fmaxf(s, -16.f), 16.f)
                               : 1.f / (1.f + __expf(-s));
            }
            *(float4*)&offmod[(((size_t)b * OCM + oc) << 12) + (h << 6) + wm + q * 4] = v;
        }
    }
}

// K2: deformable conv, producer/consumer waves, XCD-local b, distance-3
// corner prefetch. grid: 512 linear, b = idx&7, h = idx>>3.
__global__ __launch_bounds__(512, 4) void k_deform7(
    const u16* __restrict__ xbf, const float* __restrict__ offmod,
    const u16* __restrict__ w2, float* __restrict__ out)
{
    const int t = threadIdx.x;
    const int b = blockIdx.x & 7, h = blockIdx.x >> 3;
    const int lane = t & 63, wv = t >> 6;

    __shared__ int   SIDX[9][4][64];
    __shared__ float SW[9][4][64];
    __shared__ u16 AsB[2][64 * 32];
    __shared__ u16 BsB[2][256 * 32];

    // ---- sample tables: 9 taps x 64 w (all 512 threads) ----
    const float* om = offmod + (size_t)b * OCM * 4096;
    for (int e = t; e < 9 * 64; e += 512) {
        int m = e & 63, tap = e >> 6;
        float dy = om[(tap * 2) * 4096 + h * 64 + m];
        float dx = om[(tap * 2 + 1) * 4096 + h * 64 + m];
        float mv = om[(18 + tap) * 4096 + h * 64 + m];
        float py = dy + (float)(tap / 3) + (float)(h - 1);
        float px = dx + (float)(tap % 3) + (float)(m - 1);
        float y0f = floorf(py), x0f = floorf(px);
        float ly = py - y0f, lx = px - x0f;
        int y0 = (int)y0f, x0 = (int)x0f;
        int   ysr[2] = {y0, y0 + 1};
        int   xsr[2] = {x0, x0 + 1};
        float wy[2] = {1.f - ly, ly};
        float wx[2] = {1.f - lx, lx};
#pragma unroll
        for (int r = 0; r < 4; ++r) {
            int yy = ysr[r >> 1], xx = xsr[r & 1];
            bool ok = ((unsigned)yy < HH) && ((unsigned)xx < WW);
            int yc = min(max(yy, 0), HH - 1);
            int xc = min(max(xx, 0), WW - 1);
            SIDX[tap][r][m] = yc * WW + xc;
            SW[tap][r][m] = ok ? (wy[r >> 1] * wx[r & 1] * mv) : 0.f;
        }
    }
    __syncthreads();

    if (wv < 4) {
        // ================= consumers: pure MFMA =================
        const int fr = lane & 15, q = lane >> 4;
        const int wn = wv << 6;

        f4 acc[4][4];
#pragma unroll
        for (int mi = 0; mi < 4; ++mi)
#pragma unroll
            for (int ni = 0; ni < 4; ++ni) acc[mi][ni] = (f4){0.f, 0.f, 0.f, 0.f};

        for (int kt = 0; kt < NKT; ++kt) {
            const int p = kt & 1;
            BARRIER_RAW();
            frag a[4];
#pragma unroll
            for (int mi = 0; mi < 4; ++mi)
                a[mi] = *(const frag*)&AsB[p][sw_off(mi * 16 + fr, q)];
#pragma unroll
            for (int nh = 0; nh < 2; ++nh) {
                frag b0 = *(const frag*)&BsB[p][sw_off(wn + nh * 32 + fr, q)];
                frag b1 = *(const frag*)&BsB[p][sw_off(wn + nh * 32 + 16 + fr, q)];
#pragma unroll
                for (int mi = 0; mi < 4; ++mi) {
                    acc[mi][nh * 2]     = __builtin_amdgcn_mfma_f32_16x16x32_bf16(
                        a[mi], b0, acc[mi][nh * 2], 0, 0, 0);
                    acc[mi][nh * 2 + 1] = __builtin_amdgcn_mfma_f32_16x16x32_bf16(
                        a[mi], b1, acc[mi][nh * 2 + 1], 0, 0, 0);
                }
            }
        }

        // epilogue: out[b][n][h*64+w]; C/D col=fr(n), row=q*4+r(m)
#pragma unroll
        for (int ni = 0; ni < 4; ++ni) {
            int n_g = wn + ni * 16 + fr;
            float* outn = out + (((size_t)b * COUT + n_g) << 12) + (h << 6);
#pragma unroll
            for (int mi = 0; mi < 4; ++mi) {
                int wl = mi * 16 + q * 4;
                *(float4*)&outn[wl] = make_float4(acc[mi][ni][0], acc[mi][ni][1],
                                                  acc[mi][ni][2], acc[mi][ni][3]);
            }
        }
    } else {
        // ================= producers: gather + interp + staging =================
        const int pt = t - 256;            // 0..255
        const int mg = pt >> 2, oct = pt & 3;
        const int pwv = wv - 4;            // 0..3
        const int ko_sw = (lane & 3) ^ ((lane >> 3) & 3);  // matches sw_off g
        const u16* xpl = xbf + ((size_t)b << 20);

        auto stageB = [&](int kt, int buf) {
            const u16* src = w2 + ((size_t)kt << 13);
#pragma unroll
            for (int j = 0; j < 4; ++j) {
                int n = (pwv << 6) + (j << 4) + (lane >> 2);
                u16* dst = &BsB[buf][((pwv << 6) + (j << 4)) << 5];  // wave-uniform base
                gl2lds16(src + n * 32 + ko_sw * 8, dst);
            }
        };
        auto loadCorners = [&](int kt, uint4 (&cr)[4]) {
            int tap = kt >> 3;
            int c0 = ((kt & 7) << 5) + (oct << 3);
            const u16* base = xpl + c0;
#pragma unroll
            for (int r = 0; r < 4; ++r)
                cr[r] = *(const uint4*)(base + ((size_t)SIDX[tap][r][mg] << 8));
        };
        auto interpStore = [&](int kt, int buf, uint4 (&cr)[4]) {
            int tap = kt >> 3;
            float va[8];
#pragma unroll
            for (int j = 0; j < 8; ++j) va[j] = 0.f;
#pragma unroll
            for (int r = 0; r < 4; ++r) {
                float s = SW[tap][r][mg];
                u32 uu[4] = {cr[r].x, cr[r].y, cr[r].z, cr[r].w};
#pragma unroll
                for (int jj = 0; jj < 4; ++jj) {
                    va[2 * jj]     += s * __uint_as_float(uu[jj] << 16);
                    va[2 * jj + 1] += s * __uint_as_float(uu[jj] & 0xFFFF0000u);
                }
            }
            u32 pk[4];
#pragma unroll
            for (int jp = 0; jp < 4; ++jp)
                pk[jp] = (u32)f2bf(va[2 * jp]) | ((u32)f2bf(va[2 * jp + 1]) << 16);
            *(uint4*)&AsB[buf][sw_off(mg, oct)] = make_uint4(pk[0], pk[1], pk[2], pk[3]);
        };

        uint4 cr0[4], cr1[4], cr2[4];      // corners(kt) lives at slot kt%3
        // prologue: B(0)->buf0; corners 0,1,2 in flight; interp(0)->As0
        stageB(0, 0);
        loadCorners(0, cr0);
        loadCorners(1, cr1);
        loadCorners(2, cr2);
        interpStore(0, 0, cr0);
        asm volatile("s_waitcnt lgkmcnt(0)" ::: "memory");

        // pstep(kt, p): entry in-flight (oldest first) = corners(kt+1),
        // B(kt), corners(kt+2). vmcnt(4) drains corners(kt+1)+B(kt), keeps
        // corners(kt+2) flying; 2-iter slack on corners, 1-iter on B.
        auto pstep = [&](int kt, int p, uint4 (&cur)[4], uint4 (&nxt)[4]) {
            if (kt + 2 < NKT) asm volatile("s_waitcnt vmcnt(4)" ::: "memory");
            else              asm volatile("s_waitcnt vmcnt(0)" ::: "memory");
            BARRIER_RAW();
            if (kt + 1 < NKT) stageB(kt + 1, 1 - p);
            if (kt + 3 < NKT) loadCorners(kt + 3, nxt);
            if (kt + 1 < NKT) interpStore(kt + 1, 1 - p, cur);
            asm volatile("s_waitcnt lgkmcnt(0)" ::: "memory");
        };
        for (int kt = 0; kt < NKT; kt += 6) {
            pstep(kt,     0, cr1, cr0);
            pstep(kt + 1, 1, cr2, cr1);
            pstep(kt + 2, 0, cr0, cr2);
            pstep(kt + 3, 1, cr1, cr0);
            pstep(kt + 4, 0, cr2, cr1);
            pstep(kt + 5, 1, cr0, cr2);
        }
    }
}

extern "C" void kernel_launch(void* const* d_in, const int* in_sizes, int n_in,
                              void* d_out, int out_size, void* d_ws, size_t ws_size,
                              hipStream_t stream) {
    const float* x  = (const float*)d_in[0];
    const float* ow = (const float*)d_in[1];
    const float* ob = (const float*)d_in[2];
    const float* mw = (const float*)d_in[3];
    const float* mb = (const float*)d_in[4];
    const float* rw = (const float*)d_in[5];
    float* out = (float*)d_out;
    char* ws = (char*)d_ws;

    u16*   xbf    = (u16*)(ws + WS_XBF);
    u16*   w2     = (u16*)(ws + WS_W2);
    u16*   w2om   = (u16*)(ws + WS_W2OM);
    float* offmod = (float*)(ws + WS_OFFMOD);

    k_nhwc3<<<dim3(HH, BB), 256, 0, stream>>>(x, xbf);
    k_pack_w2<<<(NKT * COUT * 32 + 255) / 256, 256, 0, stream>>>(rw, w2);
    k_pack_w2om<<<(NKT * 32 * 32 + 255) / 256, 256, 0, stream>>>(ow, mw, w2om);
    k_offmod6<<<dim3(512), 512, 0, stream>>>(xbf, w2om, ob, mb, offmod);
    k_deform7<<<dim3(512), 512, 0, stream>>>(xbf, offmod, w2, out);
}